// Round 12
// baseline (187.403 us; speedup 1.0000x reference)
//
#include <hip/hip_runtime.h>

#define NN 50000
#define NE 800000
#define FD 128
#define NG 512
#define NC 10

// bucketed CSR build
#define NBUCK 196           // ceil(50000/256)
#define BSHIFT 8            // 256 nodes per bucket
#define BSTRIDE 5120        // slots per bucket region (mean 4096, sd ~64)
#define P1_EPB 4096         // edges per pass1 block
#define P1_BLOCKS ((NE + P1_EPB - 1) / P1_EPB)  // 196

typedef __attribute__((ext_vector_type(8))) short bf16x8;
typedef __attribute__((ext_vector_type(4))) float f32x4;

// ---------------- bf16 helpers ----------------

__device__ __forceinline__ unsigned short f2bf(float f) {
  unsigned int b = __float_as_uint(f);
  b += 0x7FFF + ((b >> 16) & 1);   // round-to-nearest-even
  return (unsigned short)(b >> 16);
}
__device__ __forceinline__ float blo(unsigned int u) {
  return __uint_as_float(u << 16);
}
__device__ __forceinline__ float bhi(unsigned int u) {
  return __uint_as_float(u & 0xFFFF0000u);
}

// ---------------- setup: W fragment prep (x3) + gcursor init, one launch ----------

__global__ __launch_bounds__(256) void setup_kernel(const float* __restrict__ W1,
                                                    const float* __restrict__ W2,
                                                    const float* __restrict__ W3,
                                                    unsigned short* __restrict__ wf1,
                                                    unsigned short* __restrict__ wf2,
                                                    unsigned short* __restrict__ wf3,
                                                    int* __restrict__ gcursor) {
  int idx = blockIdx.x * 256 + threadIdx.x;
  if (idx < 3 * 16384) {
    int wi = idx >> 14;
    int i = idx & 16383;
    const float* W = (wi == 0) ? W1 : (wi == 1) ? W2 : W3;
    unsigned short* wf = (wi == 0) ? wf1 : (wi == 1) ? wf2 : wf3;
    int j = i & 7, l = (i >> 3) & 63, ks = (i >> 9) & 3, ct = i >> 11;
    int k = ks * 32 + (l >> 4) * 8 + j;
    int c = ct * 16 + (l & 15);
    float w = W[k * 128 + c];
    unsigned int bb = __float_as_uint(w);
    unsigned int bh = bb & 0xFFFF0000u;
    float r = w - __uint_as_float(bh);    // exact
    int base = (((ct * 4 + ks) * 2 + 0) * 64 + l) * 8 + j;
    wf[base] = (unsigned short)(bh >> 16);
    wf[base + 512] = f2bf(r);             // lo plane
  } else {
    int t = idx - 3 * 16384;
    if (t < NBUCK) gcursor[t] = t * BSTRIDE;
  }
}
#define SETUP_BLOCKS ((3 * 16384 + NBUCK + 255) / 256)

// pass1: histogram -> per-block bucket reservation -> direct scatter.
__global__ __launch_bounds__(1024) void pass1_kernel(const int* __restrict__ ei,
                                                     int* __restrict__ gcursor,
                                                     unsigned int* __restrict__ bucketBuf) {
  __shared__ int bh[NBUCK];
  __shared__ int gbase[NBUCK];
  __shared__ int bcur[NBUCK];

  int tid = threadIdx.x;
  int e0 = blockIdx.x * P1_EPB;
  int ne = NE - e0; if (ne > P1_EPB) ne = P1_EPB;

  if (tid < NBUCK) bh[tid] = 0;
  __syncthreads();

  for (int i = tid; i < ne; i += 1024) {
    int d = ei[NE + e0 + i];
    atomicAdd(&bh[d >> BSHIFT], 1);
  }
  __syncthreads();

  if (tid < NBUCK) {
    bcur[tid] = 0;
    gbase[tid] = (bh[tid] > 0) ? atomicAdd(&gcursor[tid], bh[tid]) : 0;
  }
  __syncthreads();

  for (int i = tid; i < ne; i += 1024) {
    int s = ei[e0 + i];
    int d = ei[NE + e0 + i];
    int b = d >> BSHIFT;
    int p = atomicAdd(&bcur[b], 1);
    bucketBuf[gbase[b] + p] = (unsigned int)s | ((unsigned int)d << 16);
  }
}

// pass2: inline bucket-prefix scan; per-bucket dst-sort in LDS; derives
// degree -> dis, offs; emits u16 CSR.
__global__ __launch_bounds__(1024) void pass2_kernel(const unsigned int* __restrict__ bucketBuf,
                                                     const int* __restrict__ gcur,
                                                     int* __restrict__ offs,
                                                     float* __restrict__ dis,
                                                     unsigned short* __restrict__ csr) {
  __shared__ unsigned int raw[BSTRIDE];      // 20 KB
  __shared__ unsigned short sorted[BSTRIDE]; // 10 KB
  __shared__ int h[256], pos[256], cur[256];
  __shared__ int sarr[256];

  int b = blockIdx.x;
  int tid = threadIdx.x;
  int nStart = b << BSHIFT;

  // inline inclusive scan over the 196 bucket counts
  if (tid < 256) sarr[tid] = (tid < NBUCK) ? (gcur[tid] - tid * BSTRIDE) : 0;
  __syncthreads();
  #pragma unroll
  for (int off = 1; off < 256; off <<= 1) {
    int v = 0;
    if (tid < 256 && tid >= off) v = sarr[tid - off];
    __syncthreads();
    if (tid < 256) sarr[tid] += v;
    __syncthreads();
  }
  int cntb = gcur[b] - b * BSTRIDE;
  int cnt = (cntb > BSTRIDE) ? BSTRIDE : cntb;
  int eStart = sarr[b] - cntb;     // exclusive prefix
  if (b == NBUCK - 1 && tid == 0) offs[NN] = sarr[NBUCK - 1];  // == NE

  for (int i = tid; i < cnt; i += 1024) raw[i] = bucketBuf[(size_t)b * BSTRIDE + i];
  if (tid < 256) h[tid] = 0;
  __syncthreads();

  for (int i = tid; i < cnt; i += 1024) atomicAdd(&h[(raw[i] >> 16) - nStart], 1);
  __syncthreads();

  if (tid < 256) pos[tid] = h[tid];
  __syncthreads();
  #pragma unroll
  for (int off = 1; off < 256; off <<= 1) {
    int v = 0;
    if (tid < 256 && tid >= off) v = pos[tid - off];
    __syncthreads();
    if (tid < 256) pos[tid] += v;
    __syncthreads();
  }
  if (tid < 256) {
    int ex = pos[tid] - h[tid];
    cur[tid] = ex;
    int n = nStart + tid;
    if (n < NN) {
      offs[n] = eStart + ex;
      dis[n] = rsqrtf((float)h[tid] + 1.0f);
    }
  }
  __syncthreads();

  for (int i = tid; i < cnt; i += 1024) {
    unsigned int r = raw[i];
    int d = (int)(r >> 16) - nStart;
    int p = atomicAdd(&cur[d], 1);
    sorted[p] = (unsigned short)(r & 0xFFFFu);
  }
  __syncthreads();

  for (int i = tid; i < cnt; i += 1024) csr[eStart + i] = sorted[i];
}

// ---------------- GEMM layer1: Hs(bf16) = dis * (x @ W), x fp32, 3-term ----------

__global__ __launch_bounds__(256) void gemm_f32_kernel(const float* __restrict__ A,
                                                       const unsigned short* __restrict__ wf,
                                                       const float* __restrict__ dis,
                                                       unsigned short* __restrict__ Hs) {
  __shared__ unsigned short ldsW[32768];  // 64 KB
  int tid = threadIdx.x;
  {
    const uint4* src = reinterpret_cast<const uint4*>(wf);
    uint4* dst = reinterpret_cast<uint4*>(ldsW);
    #pragma unroll
    for (int i = 0; i < 16; ++i) dst[tid + i * 256] = src[tid + i * 256];
  }
  __syncthreads();

  int w = tid >> 6, lane = tid & 63;
  int rowbase = blockIdx.x * 128 + w * 32;
  int kgrp = lane >> 4;
  int r0 = rowbase + (lane & 15);
  int r1 = r0 + 16;
  int a0 = (r0 < NN) ? r0 : 0;
  int a1 = (r1 < NN) ? r1 : 0;

  f32x4 acc0[8], acc1[8];
  #pragma unroll
  for (int ct = 0; ct < 8; ++ct) {
    f32x4 z = {0.f, 0.f, 0.f, 0.f};
    acc0[ct] = z; acc1[ct] = z;
  }

  #pragma unroll
  for (int ks = 0; ks < 4; ++ks) {
    bf16x8 ahi0, alo0, ahi1, alo1;
    {
      const float* ap = A + (size_t)a0 * FD + ks * 32 + kgrp * 8;
      float4 v0 = *reinterpret_cast<const float4*>(ap);
      float4 v1 = *reinterpret_cast<const float4*>(ap + 4);
      float a[8] = {v0.x, v0.y, v0.z, v0.w, v1.x, v1.y, v1.z, v1.w};
      #pragma unroll
      for (int j = 0; j < 8; ++j) {
        unsigned int bb = __float_as_uint(a[j]);
        unsigned int bh = bb & 0xFFFF0000u;
        float r = a[j] - __uint_as_float(bh);
        ahi0[j] = (short)(bh >> 16);
        alo0[j] = (short)f2bf(r);
      }
    }
    {
      const float* ap = A + (size_t)a1 * FD + ks * 32 + kgrp * 8;
      float4 v0 = *reinterpret_cast<const float4*>(ap);
      float4 v1 = *reinterpret_cast<const float4*>(ap + 4);
      float a[8] = {v0.x, v0.y, v0.z, v0.w, v1.x, v1.y, v1.z, v1.w};
      #pragma unroll
      for (int j = 0; j < 8; ++j) {
        unsigned int bb = __float_as_uint(a[j]);
        unsigned int bh = bb & 0xFFFF0000u;
        float r = a[j] - __uint_as_float(bh);
        ahi1[j] = (short)(bh >> 16);
        alo1[j] = (short)f2bf(r);
      }
    }
    #pragma unroll
    for (int ct = 0; ct < 8; ++ct) {
      int off = (((ct * 4 + ks) * 2) * 64 + lane) * 8;
      bf16x8 bhiV = *reinterpret_cast<const bf16x8*>(&ldsW[off]);
      bf16x8 bloV = *reinterpret_cast<const bf16x8*>(&ldsW[off + 512]);
      acc0[ct] = __builtin_amdgcn_mfma_f32_16x16x32_bf16(ahi0, bhiV, acc0[ct], 0, 0, 0);
      acc1[ct] = __builtin_amdgcn_mfma_f32_16x16x32_bf16(ahi1, bhiV, acc1[ct], 0, 0, 0);
      acc0[ct] = __builtin_amdgcn_mfma_f32_16x16x32_bf16(alo0, bhiV, acc0[ct], 0, 0, 0);
      acc1[ct] = __builtin_amdgcn_mfma_f32_16x16x32_bf16(alo1, bhiV, acc1[ct], 0, 0, 0);
      acc0[ct] = __builtin_amdgcn_mfma_f32_16x16x32_bf16(ahi0, bloV, acc0[ct], 0, 0, 0);
      acc1[ct] = __builtin_amdgcn_mfma_f32_16x16x32_bf16(ahi1, bloV, acc1[ct], 0, 0, 0);
    }
  }

  int ccol = lane & 15;
  #pragma unroll
  for (int g = 0; g < 2; ++g) {
    int crow0 = rowbase + g * 16 + kgrp * 4;
    #pragma unroll
    for (int i = 0; i < 4; ++i) {
      int r = crow0 + i;
      if (r < NN) {
        float dv = dis[r];
        #pragma unroll
        for (int ct = 0; ct < 8; ++ct) {
          float v = g ? acc1[ct][i] : acc0[ct][i];
          Hs[(size_t)r * FD + ct * 16 + ccol] = f2bf(dv * v);
        }
      }
    }
  }
}

// ---------------- GEMM layers 2/3: Hs(bf16) = dis * (relu(Ab) @ W), Ab bf16, 2-term --

__global__ __launch_bounds__(256) void gemm_bf16_kernel(const unsigned short* __restrict__ Ab,
                                                        const unsigned short* __restrict__ wf,
                                                        const float* __restrict__ dis,
                                                        unsigned short* __restrict__ Hs) {
  __shared__ unsigned short ldsW[32768];  // 64 KB
  int tid = threadIdx.x;
  {
    const uint4* src = reinterpret_cast<const uint4*>(wf);
    uint4* dst = reinterpret_cast<uint4*>(ldsW);
    #pragma unroll
    for (int i = 0; i < 16; ++i) dst[tid + i * 256] = src[tid + i * 256];
  }
  __syncthreads();

  int w = tid >> 6, lane = tid & 63;
  int rowbase = blockIdx.x * 128 + w * 32;
  int kgrp = lane >> 4;
  int r0 = rowbase + (lane & 15);
  int r1 = r0 + 16;
  int a0 = (r0 < NN) ? r0 : 0;
  int a1 = (r1 < NN) ? r1 : 0;

  f32x4 acc0[8], acc1[8];
  #pragma unroll
  for (int ct = 0; ct < 8; ++ct) {
    f32x4 z = {0.f, 0.f, 0.f, 0.f};
    acc0[ct] = z; acc1[ct] = z;
  }

  #pragma unroll
  for (int ks = 0; ks < 4; ++ks) {
    bf16x8 av0, av1;
    {
      uint4 u = *reinterpret_cast<const uint4*>(&Ab[(size_t)a0 * FD + ks * 32 + kgrp * 8]);
      unsigned int uu[4] = {u.x, u.y, u.z, u.w};
      #pragma unroll
      for (int p = 0; p < 4; ++p) {
        unsigned short lo16 = (unsigned short)(uu[p] & 0xFFFFu);
        unsigned short hi16 = (unsigned short)(uu[p] >> 16);
        av0[2 * p + 0] = (short)(((short)lo16 < 0) ? 0 : lo16);  // relu on bf16
        av0[2 * p + 1] = (short)(((short)hi16 < 0) ? 0 : hi16);
      }
    }
    {
      uint4 u = *reinterpret_cast<const uint4*>(&Ab[(size_t)a1 * FD + ks * 32 + kgrp * 8]);
      unsigned int uu[4] = {u.x, u.y, u.z, u.w};
      #pragma unroll
      for (int p = 0; p < 4; ++p) {
        unsigned short lo16 = (unsigned short)(uu[p] & 0xFFFFu);
        unsigned short hi16 = (unsigned short)(uu[p] >> 16);
        av1[2 * p + 0] = (short)(((short)lo16 < 0) ? 0 : lo16);
        av1[2 * p + 1] = (short)(((short)hi16 < 0) ? 0 : hi16);
      }
    }
    #pragma unroll
    for (int ct = 0; ct < 8; ++ct) {
      int off = (((ct * 4 + ks) * 2) * 64 + lane) * 8;
      bf16x8 bhiV = *reinterpret_cast<const bf16x8*>(&ldsW[off]);
      bf16x8 bloV = *reinterpret_cast<const bf16x8*>(&ldsW[off + 512]);
      acc0[ct] = __builtin_amdgcn_mfma_f32_16x16x32_bf16(av0, bhiV, acc0[ct], 0, 0, 0);
      acc1[ct] = __builtin_amdgcn_mfma_f32_16x16x32_bf16(av1, bhiV, acc1[ct], 0, 0, 0);
      acc0[ct] = __builtin_amdgcn_mfma_f32_16x16x32_bf16(av0, bloV, acc0[ct], 0, 0, 0);
      acc1[ct] = __builtin_amdgcn_mfma_f32_16x16x32_bf16(av1, bloV, acc1[ct], 0, 0, 0);
    }
  }

  int ccol = lane & 15;
  #pragma unroll
  for (int g = 0; g < 2; ++g) {
    int crow0 = rowbase + g * 16 + kgrp * 4;
    #pragma unroll
    for (int i = 0; i < 4; ++i) {
      int r = crow0 + i;
      if (r < NN) {
        float dv = dis[r];
        #pragma unroll
        for (int ct = 0; ct < 8; ++ct) {
          float v = g ? acc1[ct][i] : acc0[ct][i];
          Hs[(size_t)r * FD + ct * 16 + ccol] = f2bf(dv * v);
        }
      }
    }
  }
}

// ---------------- fused aggregation (layers 1-2): 2 nodes/wave ----------------
// AGG[n] = bf16( b + dis[n] * (Hs[n] + sum_{e: dst=n} Hs[src_e]) )

#define EDGE8(acc, h)                                        \
  acc[0] += blo(h.x); acc[1] += bhi(h.x);                    \
  acc[2] += blo(h.y); acc[3] += bhi(h.y);                    \
  acc[4] += blo(h.z); acc[5] += bhi(h.z);                    \
  acc[6] += blo(h.w); acc[7] += bhi(h.w);

#define EDGE8M(acc, h, m)                                    \
  acc[0] += m * blo(h.x); acc[1] += m * bhi(h.x);            \
  acc[2] += m * blo(h.y); acc[3] += m * bhi(h.y);            \
  acc[4] += m * blo(h.z); acc[5] += m * bhi(h.z);            \
  acc[6] += m * blo(h.w); acc[7] += m * bhi(h.w);

__global__ __launch_bounds__(256) void agg_edge_kernel(const int* __restrict__ offs,
                                                       const unsigned short* __restrict__ csr,
                                                       const float* __restrict__ dis,
                                                       const unsigned short* __restrict__ Hs,
                                                       const float* __restrict__ bias,
                                                       unsigned short* __restrict__ AGG) {
  int pair = blockIdx.x * 4 + (threadIdx.x >> 6);   // wave id; 2 nodes per wave
  int n0 = pair * 2;
  if (n0 >= NN) return;
  n0 = __builtin_amdgcn_readfirstlane(n0);
  int n1 = n0 + 1;
  int lane = threadIdx.x & 63;
  int q = lane >> 4;
  int ch = (lane & 15) * 8;

  int beg0 = offs[n0], end0 = offs[n0 + 1];
  int beg1 = end0,     end1 = offs[n1 + 1];

  float a0[8], a1[8];
  #pragma unroll
  for (int k = 0; k < 8; ++k) { a0[k] = 0.f; a1[k] = 0.f; }

  if (q == 0) {
    uint4 hn = *reinterpret_cast<const uint4*>(&Hs[(size_t)n0 * FD + ch]);
    EDGE8(a0, hn);
  } else if (q == 1) {
    uint4 hn = *reinterpret_cast<const uint4*>(&Hs[(size_t)n1 * FD + ch]);
    EDGE8(a1, hn);
  }

  int j0 = beg0, j1 = beg1;
  int it = min((end0 - j0) >> 4, (end1 - j1) >> 4);
  for (int t = 0; t < it; ++t) {
    int s00 = csr[j0 + q], s01 = csr[j0 + q + 4], s02 = csr[j0 + q + 8], s03 = csr[j0 + q + 12];
    int s10 = csr[j1 + q], s11 = csr[j1 + q + 4], s12 = csr[j1 + q + 8], s13 = csr[j1 + q + 12];
    uint4 h00 = *reinterpret_cast<const uint4*>(&Hs[(size_t)s00 * FD + ch]);
    uint4 h01 = *reinterpret_cast<const uint4*>(&Hs[(size_t)s01 * FD + ch]);
    uint4 h02 = *reinterpret_cast<const uint4*>(&Hs[(size_t)s02 * FD + ch]);
    uint4 h03 = *reinterpret_cast<const uint4*>(&Hs[(size_t)s03 * FD + ch]);
    uint4 h10 = *reinterpret_cast<const uint4*>(&Hs[(size_t)s10 * FD + ch]);
    uint4 h11 = *reinterpret_cast<const uint4*>(&Hs[(size_t)s11 * FD + ch]);
    uint4 h12 = *reinterpret_cast<const uint4*>(&Hs[(size_t)s12 * FD + ch]);
    uint4 h13 = *reinterpret_cast<const uint4*>(&Hs[(size_t)s13 * FD + ch]);
    EDGE8(a0, h00); EDGE8(a0, h01); EDGE8(a0, h02); EDGE8(a0, h03);
    EDGE8(a1, h10); EDGE8(a1, h11); EDGE8(a1, h12); EDGE8(a1, h13);
    j0 += 16; j1 += 16;
  }
  for (; j0 < end0; j0 += 16) {
    int last = end0 - 1;
    int e0 = j0 + q, e1 = j0 + q + 4, e2 = j0 + q + 8, e3 = j0 + q + 12;
    int i0 = (e0 <= last) ? e0 : 0, i1 = (e1 <= last) ? e1 : 0;
    int i2 = (e2 <= last) ? e2 : 0, i3 = (e3 <= last) ? e3 : 0;
    float m0 = (e0 <= last) ? 1.f : 0.f, m1 = (e1 <= last) ? 1.f : 0.f;
    float m2 = (e2 <= last) ? 1.f : 0.f, m3 = (e3 <= last) ? 1.f : 0.f;
    int s0 = csr[i0], s1 = csr[i1], s2 = csr[i2], s3 = csr[i3];
    uint4 h0 = *reinterpret_cast<const uint4*>(&Hs[(size_t)s0 * FD + ch]);
    uint4 h1 = *reinterpret_cast<const uint4*>(&Hs[(size_t)s1 * FD + ch]);
    uint4 h2 = *reinterpret_cast<const uint4*>(&Hs[(size_t)s2 * FD + ch]);
    uint4 h3 = *reinterpret_cast<const uint4*>(&Hs[(size_t)s3 * FD + ch]);
    EDGE8M(a0, h0, m0); EDGE8M(a0, h1, m1); EDGE8M(a0, h2, m2); EDGE8M(a0, h3, m3);
  }
  for (; j1 < end1; j1 += 16) {
    int last = end1 - 1;
    int e0 = j1 + q, e1 = j1 + q + 4, e2 = j1 + q + 8, e3 = j1 + q + 12;
    int i0 = (e0 <= last) ? e0 : 0, i1 = (e1 <= last) ? e1 : 0;
    int i2 = (e2 <= last) ? e2 : 0, i3 = (e3 <= last) ? e3 : 0;
    float m0 = (e0 <= last) ? 1.f : 0.f, m1 = (e1 <= last) ? 1.f : 0.f;
    float m2 = (e2 <= last) ? 1.f : 0.f, m3 = (e3 <= last) ? 1.f : 0.f;
    int s0 = csr[i0], s1 = csr[i1], s2 = csr[i2], s3 = csr[i3];
    uint4 h0 = *reinterpret_cast<const uint4*>(&Hs[(size_t)s0 * FD + ch]);
    uint4 h1 = *reinterpret_cast<const uint4*>(&Hs[(size_t)s1 * FD + ch]);
    uint4 h2 = *reinterpret_cast<const uint4*>(&Hs[(size_t)s2 * FD + ch]);
    uint4 h3 = *reinterpret_cast<const uint4*>(&Hs[(size_t)s3 * FD + ch]);
    EDGE8M(a1, h0, m0); EDGE8M(a1, h1, m1); EDGE8M(a1, h2, m2); EDGE8M(a1, h3, m3);
  }

  #pragma unroll
  for (int k = 0; k < 8; ++k) {
    float v0 = a0[k];
    v0 += __shfl_xor(v0, 16, 64);
    v0 += __shfl_xor(v0, 32, 64);
    a0[k] = v0;
    float v1 = a1[k];
    v1 += __shfl_xor(v1, 16, 64);
    v1 += __shfl_xor(v1, 32, 64);
    a1[k] = v1;
  }

  if (q < 2) {
    int n = q ? n1 : n0;
    float dn = dis[n];
    const float* acc = q ? a1 : a0;
    float4 b0 = *reinterpret_cast<const float4*>(&bias[ch]);
    float4 b1 = *reinterpret_cast<const float4*>(&bias[ch + 4]);
    float o[8];
    o[0] = b0.x + dn * acc[0]; o[1] = b0.y + dn * acc[1];
    o[2] = b0.z + dn * acc[2]; o[3] = b0.w + dn * acc[3];
    o[4] = b1.x + dn * acc[4]; o[5] = b1.y + dn * acc[5];
    o[6] = b1.z + dn * acc[6]; o[7] = b1.w + dn * acc[7];
    uint4 pk;
    pk.x = (unsigned int)f2bf(o[0]) | ((unsigned int)f2bf(o[1]) << 16);
    pk.y = (unsigned int)f2bf(o[2]) | ((unsigned int)f2bf(o[3]) << 16);
    pk.z = (unsigned int)f2bf(o[4]) | ((unsigned int)f2bf(o[5]) << 16);
    pk.w = (unsigned int)f2bf(o[6]) | ((unsigned int)f2bf(o[7]) << 16);
    *reinterpret_cast<uint4*>(&AGG[(size_t)n * FD + ch]) = pk;
  }
}

// ---------------- fused layer-3 aggregation + pooling + classifier ----------------
// pooled[g] = sel * ( b3 + (1/cnt) * Σ_{n∈g} dis[n]·(Hs[n] + Σ_e Hs[src_e]) )
// out[g]    = pooled @ Wl + bl
// One block per graph; batch sorted -> node range contiguous; edges contiguous.

__device__ __forceinline__ int lower_bound(const int* __restrict__ b, int n, int key) {
  int lo = 0, hi = n;
  while (lo < hi) {
    int m = (lo + hi) >> 1;
    if (b[m] < key) lo = m + 1; else hi = m;
  }
  return lo;
}

__global__ __launch_bounds__(256) void agg_pool_kernel(const int* __restrict__ offs,
                                                       const unsigned short* __restrict__ csr,
                                                       const float* __restrict__ dis,
                                                       const unsigned short* __restrict__ Hs,
                                                       const float* __restrict__ b3,
                                                       const int* __restrict__ batch,
                                                       const float* __restrict__ Wl,
                                                       const float* __restrict__ bl,
                                                       float* __restrict__ out) {
  int g = blockIdx.x;
  int tid = threadIdx.x;
  int lane = tid & 63;
  int w = __builtin_amdgcn_readfirstlane(tid >> 6);
  int q = lane >> 4;
  int ch = (lane & 15) * 8;
  int start = lower_bound(batch, NN, g);
  int end = lower_bound(batch, NN, g + 1);

  float gacc[8];
  #pragma unroll
  for (int k = 0; k < 8; ++k) gacc[k] = 0.f;

  // waves stride the graph's node range
  for (int n = start + w; n < end; n += 4) {
    int beg = offs[n], endE = offs[n + 1];
    float qa[8];
    #pragma unroll
    for (int k = 0; k < 8; ++k) qa[k] = 0.f;
    if (q == 0) {
      uint4 hn = *reinterpret_cast<const uint4*>(&Hs[(size_t)n * FD + ch]);
      EDGE8(qa, hn);
    }
    int last = endE - 1;
    for (int j = beg; j < endE; j += 16) {
      int e0 = j + q, e1 = j + q + 4, e2 = j + q + 8, e3 = j + q + 12;
      int i0 = (e0 <= last) ? e0 : 0, i1 = (e1 <= last) ? e1 : 0;
      int i2 = (e2 <= last) ? e2 : 0, i3 = (e3 <= last) ? e3 : 0;
      float m0 = (e0 <= last) ? 1.f : 0.f, m1 = (e1 <= last) ? 1.f : 0.f;
      float m2 = (e2 <= last) ? 1.f : 0.f, m3 = (e3 <= last) ? 1.f : 0.f;
      int s0 = csr[i0], s1 = csr[i1], s2 = csr[i2], s3 = csr[i3];
      uint4 h0 = *reinterpret_cast<const uint4*>(&Hs[(size_t)s0 * FD + ch]);
      uint4 h1 = *reinterpret_cast<const uint4*>(&Hs[(size_t)s1 * FD + ch]);
      uint4 h2 = *reinterpret_cast<const uint4*>(&Hs[(size_t)s2 * FD + ch]);
      uint4 h3 = *reinterpret_cast<const uint4*>(&Hs[(size_t)s3 * FD + ch]);
      EDGE8M(qa, h0, m0); EDGE8M(qa, h1, m1); EDGE8M(qa, h2, m2); EDGE8M(qa, h3, m3);
    }
    float dn = dis[n];
    #pragma unroll
    for (int k = 0; k < 8; ++k) gacc[k] += dn * qa[k];
  }

  // cross-quarter reduce once per graph
  #pragma unroll
  for (int k = 0; k < 8; ++k) {
    float v = gacc[k];
    v += __shfl_xor(v, 16, 64);
    v += __shfl_xor(v, 32, 64);
    gacc[k] = v;
  }

  __shared__ float red[4][FD];
  if (q == 0) {
    #pragma unroll
    for (int k = 0; k < 8; ++k) red[w][ch + k] = gacc[k];
  }
  __syncthreads();

  if (w == 0) {
    int cnt = end - start;
    float inv = (cnt > 0) ? 1.0f / (float)cnt : 0.f;
    float sel = (cnt > 0) ? 1.f : 0.f;
    int c0 = lane * 2, c1 = lane * 2 + 1;
    float px = (red[0][c0] + red[1][c0] + red[2][c0] + red[3][c0]) * inv + sel * b3[c0];
    float py = (red[0][c1] + red[1][c1] + red[2][c1] + red[3][c1]) * inv + sel * b3[c1];
    float pc[NC];
    #pragma unroll
    for (int c = 0; c < NC; ++c)
      pc[c] = px * Wl[c0 * NC + c] + py * Wl[c1 * NC + c];
    #pragma unroll
    for (int off = 32; off > 0; off >>= 1) {
      #pragma unroll
      for (int c = 0; c < NC; ++c) pc[c] += __shfl_down(pc[c], off, 64);
    }
    if (lane == 0) {
      #pragma unroll
      for (int c = 0; c < NC; ++c) out[g * NC + c] = pc[c] + bl[c];
    }
  }
}

// ---------------- launch ----------------

extern "C" void kernel_launch(void* const* d_in, const int* in_sizes, int n_in,
                              void* d_out, int out_size, void* d_ws, size_t ws_size,
                              hipStream_t stream) {
  const float* x       = (const float*)d_in[0];
  const int* ei        = (const int*)d_in[1];    // int32 on device
  const int* batch     = (const int*)d_in[2];    // int32 on device
  const float* W1 = (const float*)d_in[3];
  const float* b1 = (const float*)d_in[4];
  const float* W2 = (const float*)d_in[5];
  const float* b2 = (const float*)d_in[6];
  const float* W3 = (const float*)d_in[7];
  const float* b3 = (const float*)d_in[8];
  const float* Wl = (const float*)d_in[9];
  const float* bl = (const float*)d_in[10];
  float* out = (float*)d_out;

  char* ws = (char*)d_ws;
  size_t o = 0;
  auto alloc = [&](size_t bytes) {
    void* p = ws + o;
    o += bytes;
    o = (o + 255) & ~(size_t)255;
    return p;
  };
  int*   offs   = (int*)  alloc((size_t)(NN + 1) * 4);
  float* dis    = (float*)alloc((size_t)NN * 4);
  int*   gcur   = (int*)  alloc((size_t)NBUCK * 4);
  unsigned int* bucketBuf = (unsigned int*)alloc((size_t)NBUCK * BSTRIDE * 4);
  unsigned short* csr  = (unsigned short*)alloc((size_t)NE * 2 + 64);
  unsigned short* hs   = (unsigned short*)alloc((size_t)NN * FD * 2);
  unsigned short* aggb = (unsigned short*)alloc((size_t)NN * FD * 2);
  unsigned short* wf1 = (unsigned short*)alloc((size_t)2 * FD * FD * 2);
  unsigned short* wf2 = (unsigned short*)alloc((size_t)2 * FD * FD * 2);
  unsigned short* wf3 = (unsigned short*)alloc((size_t)2 * FD * FD * 2);

  setup_kernel<<<SETUP_BLOCKS, 256, 0, stream>>>(W1, W2, W3, wf1, wf2, wf3, gcur);
  pass1_kernel<<<P1_BLOCKS, 1024, 0, stream>>>(ei, gcur, bucketBuf);
  pass2_kernel<<<NBUCK, 1024, 0, stream>>>(bucketBuf, gcur, offs, dis, csr);

  int gemmGrid = (NN + 127) / 128;
  int aggGrid = (NN / 2 + 3) / 4;   // 2 nodes per wave, 4 waves per block

  // layer 1
  gemm_f32_kernel<<<gemmGrid, 256, 0, stream>>>(x, wf1, dis, hs);
  agg_edge_kernel<<<aggGrid, 256, 0, stream>>>(offs, csr, dis, hs, b1, aggb);
  // layer 2
  gemm_bf16_kernel<<<gemmGrid, 256, 0, stream>>>(aggb, wf2, dis, hs);
  agg_edge_kernel<<<aggGrid, 256, 0, stream>>>(offs, csr, dis, hs, b2, aggb);
  // layer 3: GEMM then fused aggregation+pooling+classifier
  gemm_bf16_kernel<<<gemmGrid, 256, 0, stream>>>(aggb, wf3, dis, hs);
  agg_pool_kernel<<<NG, 256, 0, stream>>>(offs, csr, dis, hs, b3, batch, Wl, bl, out);
}

// Round 13
// 171.656 us; speedup vs baseline: 1.0917x; 1.0917x over previous
//
#include <hip/hip_runtime.h>

#define NN 50000
#define NE 800000
#define FD 128
#define NG 512
#define NC 10

// bucketed CSR build
#define NBUCK 196           // ceil(50000/256)
#define BSHIFT 8            // 256 nodes per bucket
#define BSTRIDE 5120        // slots per bucket region (mean 4096, sd ~64)
#define P1_EPB 4096         // edges per pass1 block
#define P1_BLOCKS ((NE + P1_EPB - 1) / P1_EPB)  // 196

typedef __attribute__((ext_vector_type(8))) short bf16x8;
typedef __attribute__((ext_vector_type(4))) float f32x4;

// ---------------- bf16 helpers ----------------

__device__ __forceinline__ unsigned short f2bf(float f) {
  unsigned int b = __float_as_uint(f);
  b += 0x7FFF + ((b >> 16) & 1);   // round-to-nearest-even
  return (unsigned short)(b >> 16);
}
__device__ __forceinline__ float blo(unsigned int u) {
  return __uint_as_float(u << 16);
}
__device__ __forceinline__ float bhi(unsigned int u) {
  return __uint_as_float(u & 0xFFFF0000u);
}

// ---------------- setup: W fragment prep (x3) + gcursor init, one launch ----------

__global__ __launch_bounds__(256) void setup_kernel(const float* __restrict__ W1,
                                                    const float* __restrict__ W2,
                                                    const float* __restrict__ W3,
                                                    unsigned short* __restrict__ wf1,
                                                    unsigned short* __restrict__ wf2,
                                                    unsigned short* __restrict__ wf3,
                                                    int* __restrict__ gcursor) {
  int idx = blockIdx.x * 256 + threadIdx.x;
  if (idx < 3 * 16384) {
    int wi = idx >> 14;
    int i = idx & 16383;
    const float* W = (wi == 0) ? W1 : (wi == 1) ? W2 : W3;
    unsigned short* wf = (wi == 0) ? wf1 : (wi == 1) ? wf2 : wf3;
    int j = i & 7, l = (i >> 3) & 63, ks = (i >> 9) & 3, ct = i >> 11;
    int k = ks * 32 + (l >> 4) * 8 + j;
    int c = ct * 16 + (l & 15);
    float w = W[k * 128 + c];
    unsigned int bb = __float_as_uint(w);
    unsigned int bh = bb & 0xFFFF0000u;
    float r = w - __uint_as_float(bh);    // exact
    int base = (((ct * 4 + ks) * 2 + 0) * 64 + l) * 8 + j;
    wf[base] = (unsigned short)(bh >> 16);
    wf[base + 512] = f2bf(r);             // lo plane
  } else {
    int t = idx - 3 * 16384;
    if (t < NBUCK) gcursor[t] = t * BSTRIDE;
  }
}
#define SETUP_BLOCKS ((3 * 16384 + NBUCK + 255) / 256)

// pass1: reg-cached edges; 4x sub-histograms (per 256-thread subgroup) to cut
// LDS-atomic serialization; per-block combined reservation; direct scatter.
__global__ __launch_bounds__(1024) void pass1_kernel(const int* __restrict__ ei,
                                                     int* __restrict__ gcursor,
                                                     unsigned int* __restrict__ bucketBuf) {
  __shared__ int bh[4][NBUCK];
  __shared__ int gbase[4][NBUCK];
  __shared__ int bcur[4][NBUCK];

  int tid = threadIdx.x;
  int sg = tid >> 8;               // subgroup 0..3
  int e0 = blockIdx.x * P1_EPB;
  int ne = NE - e0; if (ne > P1_EPB) ne = P1_EPB;

  for (int i = tid; i < 4 * NBUCK; i += 1024) (&bh[0][0])[i] = 0;
  __syncthreads();

  // register-cache this thread's 4 edges (one global read of ei)
  int ss[4], dd[4];
  #pragma unroll
  for (int k = 0; k < 4; ++k) {
    int i = tid + k * 1024;
    bool v = i < ne;
    ss[k] = v ? ei[e0 + i] : 0;
    dd[k] = v ? ei[NE + e0 + i] : -1;
  }

  #pragma unroll
  for (int k = 0; k < 4; ++k) {
    if (dd[k] >= 0) atomicAdd(&bh[sg][dd[k] >> BSHIFT], 1);
  }
  __syncthreads();

  if (tid < NBUCK) {
    int t0 = bh[0][tid], t1 = bh[1][tid], t2 = bh[2][tid], t3 = bh[3][tid];
    int tot = t0 + t1 + t2 + t3;
    int base = (tot > 0) ? atomicAdd(&gcursor[tid], tot) : 0;
    gbase[0][tid] = base;
    gbase[1][tid] = base + t0;
    gbase[2][tid] = base + t0 + t1;
    gbase[3][tid] = base + t0 + t1 + t2;
    bcur[0][tid] = 0; bcur[1][tid] = 0; bcur[2][tid] = 0; bcur[3][tid] = 0;
  }
  __syncthreads();

  #pragma unroll
  for (int k = 0; k < 4; ++k) {
    if (dd[k] >= 0) {
      int b = dd[k] >> BSHIFT;
      int p = atomicAdd(&bcur[sg][b], 1);
      bucketBuf[gbase[sg][b] + p] = (unsigned int)ss[k] | ((unsigned int)dd[k] << 16);
    }
  }
}

// pass2: inline bucket-prefix scan; per-bucket dst-sort in LDS; derives
// degree -> dis, offs; emits u16 CSR.
__global__ __launch_bounds__(1024) void pass2_kernel(const unsigned int* __restrict__ bucketBuf,
                                                     const int* __restrict__ gcur,
                                                     int* __restrict__ offs,
                                                     float* __restrict__ dis,
                                                     unsigned short* __restrict__ csr) {
  __shared__ unsigned int raw[BSTRIDE];      // 20 KB
  __shared__ unsigned short sorted[BSTRIDE]; // 10 KB
  __shared__ int h[256], pos[256], cur[256];
  __shared__ int sarr[256];

  int b = blockIdx.x;
  int tid = threadIdx.x;
  int nStart = b << BSHIFT;

  // inline inclusive scan over the 196 bucket counts
  if (tid < 256) sarr[tid] = (tid < NBUCK) ? (gcur[tid] - tid * BSTRIDE) : 0;
  __syncthreads();
  #pragma unroll
  for (int off = 1; off < 256; off <<= 1) {
    int v = 0;
    if (tid < 256 && tid >= off) v = sarr[tid - off];
    __syncthreads();
    if (tid < 256) sarr[tid] += v;
    __syncthreads();
  }
  int cntb = gcur[b] - b * BSTRIDE;
  int cnt = (cntb > BSTRIDE) ? BSTRIDE : cntb;
  int eStart = sarr[b] - cntb;     // exclusive prefix
  if (b == NBUCK - 1 && tid == 0) offs[NN] = sarr[NBUCK - 1];  // == NE

  for (int i = tid; i < cnt; i += 1024) raw[i] = bucketBuf[(size_t)b * BSTRIDE + i];
  if (tid < 256) h[tid] = 0;
  __syncthreads();

  for (int i = tid; i < cnt; i += 1024) atomicAdd(&h[(raw[i] >> 16) - nStart], 1);
  __syncthreads();

  if (tid < 256) pos[tid] = h[tid];
  __syncthreads();
  #pragma unroll
  for (int off = 1; off < 256; off <<= 1) {
    int v = 0;
    if (tid < 256 && tid >= off) v = pos[tid - off];
    __syncthreads();
    if (tid < 256) pos[tid] += v;
    __syncthreads();
  }
  if (tid < 256) {
    int ex = pos[tid] - h[tid];
    cur[tid] = ex;
    int n = nStart + tid;
    if (n < NN) {
      offs[n] = eStart + ex;
      dis[n] = rsqrtf((float)h[tid] + 1.0f);
    }
  }
  __syncthreads();

  for (int i = tid; i < cnt; i += 1024) {
    unsigned int r = raw[i];
    int d = (int)(r >> 16) - nStart;
    int p = atomicAdd(&cur[d], 1);
    sorted[p] = (unsigned short)(r & 0xFFFFu);
  }
  __syncthreads();

  for (int i = tid; i < cnt; i += 1024) csr[eStart + i] = sorted[i];
}

// ---------------- GEMM layer1: Hs(bf16) = dis * (x @ W), x fp32, 3-term ----------

__global__ __launch_bounds__(256) void gemm_f32_kernel(const float* __restrict__ A,
                                                       const unsigned short* __restrict__ wf,
                                                       const float* __restrict__ dis,
                                                       unsigned short* __restrict__ Hs) {
  __shared__ unsigned short ldsW[32768];  // 64 KB
  int tid = threadIdx.x;
  {
    const uint4* src = reinterpret_cast<const uint4*>(wf);
    uint4* dst = reinterpret_cast<uint4*>(ldsW);
    #pragma unroll
    for (int i = 0; i < 16; ++i) dst[tid + i * 256] = src[tid + i * 256];
  }
  __syncthreads();

  int w = tid >> 6, lane = tid & 63;
  int rowbase = blockIdx.x * 128 + w * 32;
  int kgrp = lane >> 4;
  int r0 = rowbase + (lane & 15);
  int r1 = r0 + 16;
  int a0 = (r0 < NN) ? r0 : 0;
  int a1 = (r1 < NN) ? r1 : 0;

  f32x4 acc0[8], acc1[8];
  #pragma unroll
  for (int ct = 0; ct < 8; ++ct) {
    f32x4 z = {0.f, 0.f, 0.f, 0.f};
    acc0[ct] = z; acc1[ct] = z;
  }

  #pragma unroll
  for (int ks = 0; ks < 4; ++ks) {
    bf16x8 ahi0, alo0, ahi1, alo1;
    {
      const float* ap = A + (size_t)a0 * FD + ks * 32 + kgrp * 8;
      float4 v0 = *reinterpret_cast<const float4*>(ap);
      float4 v1 = *reinterpret_cast<const float4*>(ap + 4);
      float a[8] = {v0.x, v0.y, v0.z, v0.w, v1.x, v1.y, v1.z, v1.w};
      #pragma unroll
      for (int j = 0; j < 8; ++j) {
        unsigned int bb = __float_as_uint(a[j]);
        unsigned int bh = bb & 0xFFFF0000u;
        float r = a[j] - __uint_as_float(bh);
        ahi0[j] = (short)(bh >> 16);
        alo0[j] = (short)f2bf(r);
      }
    }
    {
      const float* ap = A + (size_t)a1 * FD + ks * 32 + kgrp * 8;
      float4 v0 = *reinterpret_cast<const float4*>(ap);
      float4 v1 = *reinterpret_cast<const float4*>(ap + 4);
      float a[8] = {v0.x, v0.y, v0.z, v0.w, v1.x, v1.y, v1.z, v1.w};
      #pragma unroll
      for (int j = 0; j < 8; ++j) {
        unsigned int bb = __float_as_uint(a[j]);
        unsigned int bh = bb & 0xFFFF0000u;
        float r = a[j] - __uint_as_float(bh);
        ahi1[j] = (short)(bh >> 16);
        alo1[j] = (short)f2bf(r);
      }
    }
    #pragma unroll
    for (int ct = 0; ct < 8; ++ct) {
      int off = (((ct * 4 + ks) * 2) * 64 + lane) * 8;
      bf16x8 bhiV = *reinterpret_cast<const bf16x8*>(&ldsW[off]);
      bf16x8 bloV = *reinterpret_cast<const bf16x8*>(&ldsW[off + 512]);
      acc0[ct] = __builtin_amdgcn_mfma_f32_16x16x32_bf16(ahi0, bhiV, acc0[ct], 0, 0, 0);
      acc1[ct] = __builtin_amdgcn_mfma_f32_16x16x32_bf16(ahi1, bhiV, acc1[ct], 0, 0, 0);
      acc0[ct] = __builtin_amdgcn_mfma_f32_16x16x32_bf16(alo0, bhiV, acc0[ct], 0, 0, 0);
      acc1[ct] = __builtin_amdgcn_mfma_f32_16x16x32_bf16(alo1, bhiV, acc1[ct], 0, 0, 0);
      acc0[ct] = __builtin_amdgcn_mfma_f32_16x16x32_bf16(ahi0, bloV, acc0[ct], 0, 0, 0);
      acc1[ct] = __builtin_amdgcn_mfma_f32_16x16x32_bf16(ahi1, bloV, acc1[ct], 0, 0, 0);
    }
  }

  int ccol = lane & 15;
  #pragma unroll
  for (int g = 0; g < 2; ++g) {
    int crow0 = rowbase + g * 16 + kgrp * 4;
    #pragma unroll
    for (int i = 0; i < 4; ++i) {
      int r = crow0 + i;
      if (r < NN) {
        float dv = dis[r];
        #pragma unroll
        for (int ct = 0; ct < 8; ++ct) {
          float v = g ? acc1[ct][i] : acc0[ct][i];
          Hs[(size_t)r * FD + ct * 16 + ccol] = f2bf(dv * v);
        }
      }
    }
  }
}

// ---------------- GEMM layers 2/3: Hs(bf16) = dis * (relu(Ab) @ W), Ab bf16, 2-term --

__global__ __launch_bounds__(256) void gemm_bf16_kernel(const unsigned short* __restrict__ Ab,
                                                        const unsigned short* __restrict__ wf,
                                                        const float* __restrict__ dis,
                                                        unsigned short* __restrict__ Hs) {
  __shared__ unsigned short ldsW[32768];  // 64 KB
  int tid = threadIdx.x;
  {
    const uint4* src = reinterpret_cast<const uint4*>(wf);
    uint4* dst = reinterpret_cast<uint4*>(ldsW);
    #pragma unroll
    for (int i = 0; i < 16; ++i) dst[tid + i * 256] = src[tid + i * 256];
  }
  __syncthreads();

  int w = tid >> 6, lane = tid & 63;
  int rowbase = blockIdx.x * 128 + w * 32;
  int kgrp = lane >> 4;
  int r0 = rowbase + (lane & 15);
  int r1 = r0 + 16;
  int a0 = (r0 < NN) ? r0 : 0;
  int a1 = (r1 < NN) ? r1 : 0;

  f32x4 acc0[8], acc1[8];
  #pragma unroll
  for (int ct = 0; ct < 8; ++ct) {
    f32x4 z = {0.f, 0.f, 0.f, 0.f};
    acc0[ct] = z; acc1[ct] = z;
  }

  #pragma unroll
  for (int ks = 0; ks < 4; ++ks) {
    bf16x8 av0, av1;
    {
      uint4 u = *reinterpret_cast<const uint4*>(&Ab[(size_t)a0 * FD + ks * 32 + kgrp * 8]);
      unsigned int uu[4] = {u.x, u.y, u.z, u.w};
      #pragma unroll
      for (int p = 0; p < 4; ++p) {
        unsigned short lo16 = (unsigned short)(uu[p] & 0xFFFFu);
        unsigned short hi16 = (unsigned short)(uu[p] >> 16);
        av0[2 * p + 0] = (short)(((short)lo16 < 0) ? 0 : lo16);  // relu on bf16
        av0[2 * p + 1] = (short)(((short)hi16 < 0) ? 0 : hi16);
      }
    }
    {
      uint4 u = *reinterpret_cast<const uint4*>(&Ab[(size_t)a1 * FD + ks * 32 + kgrp * 8]);
      unsigned int uu[4] = {u.x, u.y, u.z, u.w};
      #pragma unroll
      for (int p = 0; p < 4; ++p) {
        unsigned short lo16 = (unsigned short)(uu[p] & 0xFFFFu);
        unsigned short hi16 = (unsigned short)(uu[p] >> 16);
        av1[2 * p + 0] = (short)(((short)lo16 < 0) ? 0 : lo16);
        av1[2 * p + 1] = (short)(((short)hi16 < 0) ? 0 : hi16);
      }
    }
    #pragma unroll
    for (int ct = 0; ct < 8; ++ct) {
      int off = (((ct * 4 + ks) * 2) * 64 + lane) * 8;
      bf16x8 bhiV = *reinterpret_cast<const bf16x8*>(&ldsW[off]);
      bf16x8 bloV = *reinterpret_cast<const bf16x8*>(&ldsW[off + 512]);
      acc0[ct] = __builtin_amdgcn_mfma_f32_16x16x32_bf16(av0, bhiV, acc0[ct], 0, 0, 0);
      acc1[ct] = __builtin_amdgcn_mfma_f32_16x16x32_bf16(av1, bhiV, acc1[ct], 0, 0, 0);
      acc0[ct] = __builtin_amdgcn_mfma_f32_16x16x32_bf16(av0, bloV, acc0[ct], 0, 0, 0);
      acc1[ct] = __builtin_amdgcn_mfma_f32_16x16x32_bf16(av1, bloV, acc1[ct], 0, 0, 0);
    }
  }

  int ccol = lane & 15;
  #pragma unroll
  for (int g = 0; g < 2; ++g) {
    int crow0 = rowbase + g * 16 + kgrp * 4;
    #pragma unroll
    for (int i = 0; i < 4; ++i) {
      int r = crow0 + i;
      if (r < NN) {
        float dv = dis[r];
        #pragma unroll
        for (int ct = 0; ct < 8; ++ct) {
          float v = g ? acc1[ct][i] : acc0[ct][i];
          Hs[(size_t)r * FD + ct * 16 + ccol] = f2bf(dv * v);
        }
      }
    }
  }
}

// ---------------- fused aggregation: 2 nodes per wave, 8 gathers in flight ----------
// AGG[n] = bf16( b + dis[n] * (Hs[n] + sum_{e: dst=n} Hs[src_e]) )

#define EDGE8(acc, h)                                        \
  acc[0] += blo(h.x); acc[1] += bhi(h.x);                    \
  acc[2] += blo(h.y); acc[3] += bhi(h.y);                    \
  acc[4] += blo(h.z); acc[5] += bhi(h.z);                    \
  acc[6] += blo(h.w); acc[7] += bhi(h.w);

#define EDGE8M(acc, h, m)                                    \
  acc[0] += m * blo(h.x); acc[1] += m * bhi(h.x);            \
  acc[2] += m * blo(h.y); acc[3] += m * bhi(h.y);            \
  acc[4] += m * blo(h.z); acc[5] += m * bhi(h.z);            \
  acc[6] += m * blo(h.w); acc[7] += m * bhi(h.w);

__global__ __launch_bounds__(256) void agg_edge_kernel(const int* __restrict__ offs,
                                                       const unsigned short* __restrict__ csr,
                                                       const float* __restrict__ dis,
                                                       const unsigned short* __restrict__ Hs,
                                                       const float* __restrict__ bias,
                                                       unsigned short* __restrict__ AGG) {
  int pair = blockIdx.x * 4 + (threadIdx.x >> 6);   // wave id; 2 nodes per wave
  int n0 = pair * 2;
  if (n0 >= NN) return;
  n0 = __builtin_amdgcn_readfirstlane(n0);
  int n1 = n0 + 1;
  int lane = threadIdx.x & 63;
  int q = lane >> 4;
  int ch = (lane & 15) * 8;

  int beg0 = offs[n0], end0 = offs[n0 + 1];
  int beg1 = end0,     end1 = offs[n1 + 1];

  float a0[8], a1[8];
  #pragma unroll
  for (int k = 0; k < 8; ++k) { a0[k] = 0.f; a1[k] = 0.f; }

  if (q == 0) {
    uint4 hn = *reinterpret_cast<const uint4*>(&Hs[(size_t)n0 * FD + ch]);
    EDGE8(a0, hn);
  } else if (q == 1) {
    uint4 hn = *reinterpret_cast<const uint4*>(&Hs[(size_t)n1 * FD + ch]);
    EDGE8(a1, hn);
  }

  int j0 = beg0, j1 = beg1;
  int it = min((end0 - j0) >> 4, (end1 - j1) >> 4);
  for (int t = 0; t < it; ++t) {
    int s00 = csr[j0 + q], s01 = csr[j0 + q + 4], s02 = csr[j0 + q + 8], s03 = csr[j0 + q + 12];
    int s10 = csr[j1 + q], s11 = csr[j1 + q + 4], s12 = csr[j1 + q + 8], s13 = csr[j1 + q + 12];
    uint4 h00 = *reinterpret_cast<const uint4*>(&Hs[(size_t)s00 * FD + ch]);
    uint4 h01 = *reinterpret_cast<const uint4*>(&Hs[(size_t)s01 * FD + ch]);
    uint4 h02 = *reinterpret_cast<const uint4*>(&Hs[(size_t)s02 * FD + ch]);
    uint4 h03 = *reinterpret_cast<const uint4*>(&Hs[(size_t)s03 * FD + ch]);
    uint4 h10 = *reinterpret_cast<const uint4*>(&Hs[(size_t)s10 * FD + ch]);
    uint4 h11 = *reinterpret_cast<const uint4*>(&Hs[(size_t)s11 * FD + ch]);
    uint4 h12 = *reinterpret_cast<const uint4*>(&Hs[(size_t)s12 * FD + ch]);
    uint4 h13 = *reinterpret_cast<const uint4*>(&Hs[(size_t)s13 * FD + ch]);
    EDGE8(a0, h00); EDGE8(a0, h01); EDGE8(a0, h02); EDGE8(a0, h03);
    EDGE8(a1, h10); EDGE8(a1, h11); EDGE8(a1, h12); EDGE8(a1, h13);
    j0 += 16; j1 += 16;
  }
  for (; j0 < end0; j0 += 16) {
    int last = end0 - 1;
    int e0 = j0 + q, e1 = j0 + q + 4, e2 = j0 + q + 8, e3 = j0 + q + 12;
    int i0 = (e0 <= last) ? e0 : 0, i1 = (e1 <= last) ? e1 : 0;
    int i2 = (e2 <= last) ? e2 : 0, i3 = (e3 <= last) ? e3 : 0;
    float m0 = (e0 <= last) ? 1.f : 0.f, m1 = (e1 <= last) ? 1.f : 0.f;
    float m2 = (e2 <= last) ? 1.f : 0.f, m3 = (e3 <= last) ? 1.f : 0.f;
    int s0 = csr[i0], s1 = csr[i1], s2 = csr[i2], s3 = csr[i3];
    uint4 h0 = *reinterpret_cast<const uint4*>(&Hs[(size_t)s0 * FD + ch]);
    uint4 h1 = *reinterpret_cast<const uint4*>(&Hs[(size_t)s1 * FD + ch]);
    uint4 h2 = *reinterpret_cast<const uint4*>(&Hs[(size_t)s2 * FD + ch]);
    uint4 h3 = *reinterpret_cast<const uint4*>(&Hs[(size_t)s3 * FD + ch]);
    EDGE8M(a0, h0, m0); EDGE8M(a0, h1, m1); EDGE8M(a0, h2, m2); EDGE8M(a0, h3, m3);
  }
  for (; j1 < end1; j1 += 16) {
    int last = end1 - 1;
    int e0 = j1 + q, e1 = j1 + q + 4, e2 = j1 + q + 8, e3 = j1 + q + 12;
    int i0 = (e0 <= last) ? e0 : 0, i1 = (e1 <= last) ? e1 : 0;
    int i2 = (e2 <= last) ? e2 : 0, i3 = (e3 <= last) ? e3 : 0;
    float m0 = (e0 <= last) ? 1.f : 0.f, m1 = (e1 <= last) ? 1.f : 0.f;
    float m2 = (e2 <= last) ? 1.f : 0.f, m3 = (e3 <= last) ? 1.f : 0.f;
    int s0 = csr[i0], s1 = csr[i1], s2 = csr[i2], s3 = csr[i3];
    uint4 h0 = *reinterpret_cast<const uint4*>(&Hs[(size_t)s0 * FD + ch]);
    uint4 h1 = *reinterpret_cast<const uint4*>(&Hs[(size_t)s1 * FD + ch]);
    uint4 h2 = *reinterpret_cast<const uint4*>(&Hs[(size_t)s2 * FD + ch]);
    uint4 h3 = *reinterpret_cast<const uint4*>(&Hs[(size_t)s3 * FD + ch]);
    EDGE8M(a1, h0, m0); EDGE8M(a1, h1, m1); EDGE8M(a1, h2, m2); EDGE8M(a1, h3, m3);
  }

  #pragma unroll
  for (int k = 0; k < 8; ++k) {
    float v0 = a0[k];
    v0 += __shfl_xor(v0, 16, 64);
    v0 += __shfl_xor(v0, 32, 64);
    a0[k] = v0;
    float v1 = a1[k];
    v1 += __shfl_xor(v1, 16, 64);
    v1 += __shfl_xor(v1, 32, 64);
    a1[k] = v1;
  }

  if (q < 2) {
    int n = q ? n1 : n0;
    float dn = dis[n];
    const float* acc = q ? a1 : a0;
    float4 b0 = *reinterpret_cast<const float4*>(&bias[ch]);
    float4 b1 = *reinterpret_cast<const float4*>(&bias[ch + 4]);
    float o[8];
    o[0] = b0.x + dn * acc[0]; o[1] = b0.y + dn * acc[1];
    o[2] = b0.z + dn * acc[2]; o[3] = b0.w + dn * acc[3];
    o[4] = b1.x + dn * acc[4]; o[5] = b1.y + dn * acc[5];
    o[6] = b1.z + dn * acc[6]; o[7] = b1.w + dn * acc[7];
    uint4 pk;
    pk.x = (unsigned int)f2bf(o[0]) | ((unsigned int)f2bf(o[1]) << 16);
    pk.y = (unsigned int)f2bf(o[2]) | ((unsigned int)f2bf(o[3]) << 16);
    pk.z = (unsigned int)f2bf(o[4]) | ((unsigned int)f2bf(o[5]) << 16);
    pk.w = (unsigned int)f2bf(o[6]) | ((unsigned int)f2bf(o[7]) << 16);
    *reinterpret_cast<uint4*>(&AGG[(size_t)n * FD + ch]) = pk;
  }
}

// ---------------- fused pooling + classifier (bf16 AGG input) ----------------

__device__ __forceinline__ int lower_bound(const int* __restrict__ b, int n, int key) {
  int lo = 0, hi = n;
  while (lo < hi) {
    int m = (lo + hi) >> 1;
    if (b[m] < key) lo = m + 1; else hi = m;
  }
  return lo;
}

__global__ __launch_bounds__(256) void pool_final_kernel(const unsigned short* __restrict__ AGG,
                                                         const int* __restrict__ batch,
                                                         const float* __restrict__ Wl,
                                                         const float* __restrict__ bl,
                                                         float* __restrict__ out) {
  int g = blockIdx.x;
  int tid = threadIdx.x;
  int lane = tid & 63, w = tid >> 6;
  int start = lower_bound(batch, NN, g);
  int end = lower_bound(batch, NN, g + 1);

  float2 acc = make_float2(0.f, 0.f);
  for (int n = start + w; n < end; n += 4) {
    unsigned int v = *reinterpret_cast<const unsigned int*>(&AGG[(size_t)n * FD + lane * 2]);
    acc.x += blo(v);
    acc.y += bhi(v);
  }
  __shared__ float red[4][FD];
  red[w][lane * 2 + 0] = acc.x;
  red[w][lane * 2 + 1] = acc.y;
  __syncthreads();
  if (w == 0) {
    float px = red[0][lane * 2] + red[1][lane * 2] + red[2][lane * 2] + red[3][lane * 2];
    float py = red[0][lane * 2 + 1] + red[1][lane * 2 + 1] + red[2][lane * 2 + 1] + red[3][lane * 2 + 1];
    float inv = 1.0f / fmaxf((float)(end - start), 1.0f);
    px *= inv; py *= inv;
    float pc[NC];
    #pragma unroll
    for (int c = 0; c < NC; ++c)
      pc[c] = px * Wl[(2 * lane) * NC + c] + py * Wl[(2 * lane + 1) * NC + c];
    #pragma unroll
    for (int off = 32; off > 0; off >>= 1) {
      #pragma unroll
      for (int c = 0; c < NC; ++c) pc[c] += __shfl_down(pc[c], off, 64);
    }
    if (lane == 0) {
      #pragma unroll
      for (int c = 0; c < NC; ++c) out[g * NC + c] = pc[c] + bl[c];
    }
  }
}

// ---------------- launch ----------------

extern "C" void kernel_launch(void* const* d_in, const int* in_sizes, int n_in,
                              void* d_out, int out_size, void* d_ws, size_t ws_size,
                              hipStream_t stream) {
  const float* x       = (const float*)d_in[0];
  const int* ei        = (const int*)d_in[1];    // int32 on device
  const int* batch     = (const int*)d_in[2];    // int32 on device
  const float* W1 = (const float*)d_in[3];
  const float* b1 = (const float*)d_in[4];
  const float* W2 = (const float*)d_in[5];
  const float* b2 = (const float*)d_in[6];
  const float* W3 = (const float*)d_in[7];
  const float* b3 = (const float*)d_in[8];
  const float* Wl = (const float*)d_in[9];
  const float* bl = (const float*)d_in[10];
  float* out = (float*)d_out;

  char* ws = (char*)d_ws;
  size_t o = 0;
  auto alloc = [&](size_t bytes) {
    void* p = ws + o;
    o += bytes;
    o = (o + 255) & ~(size_t)255;
    return p;
  };
  int*   offs   = (int*)  alloc((size_t)(NN + 1) * 4);
  float* dis    = (float*)alloc((size_t)NN * 4);
  int*   gcur   = (int*)  alloc((size_t)NBUCK * 4);
  unsigned int* bucketBuf = (unsigned int*)alloc((size_t)NBUCK * BSTRIDE * 4);
  unsigned short* csr  = (unsigned short*)alloc((size_t)NE * 2 + 64);
  unsigned short* hs   = (unsigned short*)alloc((size_t)NN * FD * 2);
  unsigned short* aggb = (unsigned short*)alloc((size_t)NN * FD * 2);
  unsigned short* wf1 = (unsigned short*)alloc((size_t)2 * FD * FD * 2);
  unsigned short* wf2 = (unsigned short*)alloc((size_t)2 * FD * FD * 2);
  unsigned short* wf3 = (unsigned short*)alloc((size_t)2 * FD * FD * 2);

  setup_kernel<<<SETUP_BLOCKS, 256, 0, stream>>>(W1, W2, W3, wf1, wf2, wf3, gcur);
  pass1_kernel<<<P1_BLOCKS, 1024, 0, stream>>>(ei, gcur, bucketBuf);
  pass2_kernel<<<NBUCK, 1024, 0, stream>>>(bucketBuf, gcur, offs, dis, csr);

  int gemmGrid = (NN + 127) / 128;
  int aggGrid = (NN / 2 + 3) / 4;   // 2 nodes per wave, 4 waves per block

  // layer 1
  gemm_f32_kernel<<<gemmGrid, 256, 0, stream>>>(x, wf1, dis, hs);
  agg_edge_kernel<<<aggGrid, 256, 0, stream>>>(offs, csr, dis, hs, b1, aggb);
  // layer 2
  gemm_bf16_kernel<<<gemmGrid, 256, 0, stream>>>(aggb, wf2, dis, hs);
  agg_edge_kernel<<<aggGrid, 256, 0, stream>>>(offs, csr, dis, hs, b2, aggb);
  // layer 3
  gemm_bf16_kernel<<<gemmGrid, 256, 0, stream>>>(aggb, wf3, dis, hs);
  agg_edge_kernel<<<aggGrid, 256, 0, stream>>>(offs, csr, dis, hs, b3, aggb);

  pool_final_kernel<<<NG, 256, 0, stream>>>(aggb, batch, Wl, bl, out);
}